// Round 1
// baseline (581.850 us; speedup 1.0000x reference)
//
#include <hip/hip_runtime.h>
#include <cstdint>
#include <cstddef>

#define C_N     21
#define BZ      4
#define TOKEN_N 1024
#define TOTAL_N 1025
#define PROB_ELEMS (BZ * TOKEN_N * C_N)   // 86016

// unaligned-capable float4 (4-byte aligned): compiler splits into dword loads
struct __attribute__((packed, aligned(4))) f4u { float x, y, z, w; };

// ---------------- kernel 1: softmax over C for each (b, token) ----------------
__global__ __launch_bounds__(256) void softmax_kernel(const float* __restrict__ preds,
                                                      float* __restrict__ prob) {
    int t = blockIdx.x * blockDim.x + threadIdx.x;   // 0 .. BZ*TOKEN_N-1
    if (t >= BZ * TOKEN_N) return;
    int b = t >> 10, j = t & 1023;
    const float* p = preds + (size_t)b * C_N * TOKEN_N + j;
    float v[C_N];
    float mx = -3.4e38f;
#pragma unroll
    for (int c = 0; c < C_N; ++c) { v[c] = p[(size_t)c * TOKEN_N]; mx = fmaxf(mx, v[c]); }
    float ss = 0.f;
#pragma unroll
    for (int c = 0; c < C_N; ++c) { v[c] = __expf(v[c] - mx); ss += v[c]; }
    float inv = 1.f / ss;
    float* o = prob + (size_t)t * C_N;
#pragma unroll
    for (int c = 0; c < C_N; ++c) o[c] = v[c] * inv;
}

// ---------------- kernel 2: the streaming pass over all attention rows ----------------
// row r -> matrix m = r>>10 (0..127: first 64 = enc slices of attns, next 64 = dec),
// row index i = r&1023. Computes d[c] = sum_j a[j]*prob[b,j,c], s = sum_j a[j],
// accumulates acc[b,i,c] += d[c]/s.
__global__ __launch_bounds__(256) void rows_kernel(const float* __restrict__ attns,
                                                   const float* __restrict__ dattns,
                                                   const float* __restrict__ prob,
                                                   float* __restrict__ acc) {
    int r = blockIdx.x * 256 + threadIdx.x;          // 0 .. 131071
    int m = r >> 10;                                  // wave/block-uniform
    int i = r & 1023;
    float d[C_N];
#pragma unroll
    for (int c = 0; c < C_N; ++c) d[c] = 0.f;
    float s = 0.f;
    int b;

    if (m < 64) {
        // enc: attns[l,b,h, 1+i, 1+j]; m = (l*4+b)*8 + h
        b = (m >> 3) & 3;
        const float* rowp = attns + (size_t)m * (TOTAL_N * TOTAL_N)
                                  + (size_t)(i + 1) * TOTAL_N + 1;
        const float* probB = prob + (size_t)b * (TOKEN_N * C_N);
#pragma unroll 2
        for (int j = 0; j < TOKEN_N; j += 4) {
            f4u a = *reinterpret_cast<const f4u*>(rowp + j);
            int off = __builtin_amdgcn_readfirstlane(j * C_N);   // force SGPR offset
            const float* pp = probB + off;
            s += (a.x + a.y) + (a.z + a.w);
#pragma unroll
            for (int c = 0; c < C_N; ++c) {
                float t0 = fmaf(a.x, pp[c], d[c]);
                t0 = fmaf(a.y, pp[c + C_N], t0);
                t0 = fmaf(a.z, pp[c + 2 * C_N], t0);
                d[c] = fmaf(a.w, pp[c + 3 * C_N], t0);
            }
        }
    } else {
        // dec: decode_attns[l,b,h, i, j]; 16B-aligned rows
        int md = m - 64;
        b = (md >> 3) & 3;
        const float* rowp = dattns + (size_t)md * (TOKEN_N * TOKEN_N) + (size_t)i * TOKEN_N;
        const float* probB = prob + (size_t)b * (TOKEN_N * C_N);
#pragma unroll 2
        for (int j = 0; j < TOKEN_N; j += 4) {
            float4 a = *reinterpret_cast<const float4*>(rowp + j);
            int off = __builtin_amdgcn_readfirstlane(j * C_N);
            const float* pp = probB + off;
            s += (a.x + a.y) + (a.z + a.w);
#pragma unroll
            for (int c = 0; c < C_N; ++c) {
                float t0 = fmaf(a.x, pp[c], d[c]);
                t0 = fmaf(a.y, pp[c + C_N], t0);
                t0 = fmaf(a.z, pp[c + 2 * C_N], t0);
                d[c] = fmaf(a.w, pp[c + 3 * C_N], t0);
            }
        }
    }

    float invs = 1.f / s;
    float* ao = acc + ((size_t)b * TOKEN_N + i) * C_N;
#pragma unroll
    for (int c = 0; c < C_N; ++c) unsafeAtomicAdd(&ao[c], d[c] * invs);
}

// ---------------- kernel 3: masked L1 loss + ROI count, block-reduced ----------------
__global__ __launch_bounds__(256) void loss_kernel(const float* __restrict__ prob,
                                                   const float* __restrict__ acc,
                                                   const int* __restrict__ roi,
                                                   float* __restrict__ scal) {
    int t = blockIdx.x * 256 + threadIdx.x;          // 0 .. BZ*TOKEN_N-1
    float lossp = 0.f, np = 0.f;
    if (t < BZ * TOKEN_N) {
        int rv = roi[t];
        np = (float)rv;
        const float* a = acc + (size_t)t * C_N;
        const float* p = prob + (size_t)t * C_N;
        float S = 0.f;
#pragma unroll
        for (int c = 0; c < C_N; ++c) S += a[c];
        float invS = 1.f / S;
        float l = 0.f;
#pragma unroll
        for (int c = 0; c < C_N; ++c) l += fabsf(p[c] - a[c] * invS);
        lossp = rv ? l : 0.f;
    }
    // wave reduce (64 lanes)
#pragma unroll
    for (int off = 32; off > 0; off >>= 1) {
        lossp += __shfl_down(lossp, off);
        np    += __shfl_down(np, off);
    }
    __shared__ float redL[4], redN[4];
    int lane = threadIdx.x & 63, wv = threadIdx.x >> 6;
    if (lane == 0) { redL[wv] = lossp; redN[wv] = np; }
    __syncthreads();
    if (threadIdx.x == 0) {
        float L  = redL[0] + redL[1] + redL[2] + redL[3];
        float NN = redN[0] + redN[1] + redN[2] + redN[3];
        unsafeAtomicAdd(&scal[0], L);
        unsafeAtomicAdd(&scal[1], NN);
    }
}

// ---------------- kernel 4: finalize scalar ----------------
__global__ void finalize_kernel(const float* __restrict__ scal, float* __restrict__ out) {
    float loss = scal[0], N = scal[1];
    out[0] = (N > 0.f) ? (loss / N) : loss;   // WEIGHT = 1.0
}

extern "C" void kernel_launch(void* const* d_in, const int* in_sizes, int n_in,
                              void* d_out, int out_size, void* d_ws, size_t ws_size,
                              hipStream_t stream) {
    const float* preds  = (const float*)d_in[0];
    const int*   roi    = (const int*)d_in[3];
    const float* attns  = (const float*)d_in[5];
    const float* dattns = (const float*)d_in[6];

    float* prob = (float*)d_ws;               // 86016 floats
    float* acc  = prob + PROB_ELEMS;          // 86016 floats
    float* scal = acc + PROB_ELEMS;           // 2 floats (loss, N)

    hipMemsetAsync(acc, 0, (PROB_ELEMS + 2) * sizeof(float), stream);

    hipLaunchKernelGGL(softmax_kernel, dim3((BZ * TOKEN_N + 255) / 256), dim3(256), 0, stream,
                       preds, prob);
    hipLaunchKernelGGL(rows_kernel, dim3(512), dim3(256), 0, stream,
                       attns, dattns, prob, acc);
    hipLaunchKernelGGL(loss_kernel, dim3((BZ * TOKEN_N + 255) / 256), dim3(256), 0, stream,
                       prob, acc, roi, scal);
    hipLaunchKernelGGL(finalize_kernel, dim3(1), dim3(1), 0, stream,
                       scal, (float*)d_out);
}

// Round 2
// 295.953 us; speedup vs baseline: 1.9660x; 1.9660x over previous
//
#include <hip/hip_runtime.h>
#include <cstdint>
#include <cstddef>

#define C_N     21
#define BZ      4
#define TOKEN_N 1024
#define TOTAL_N 1025
#define PROB_ELEMS (BZ * TOKEN_N * C_N)   // 86016

// unaligned-capable float4 (4-byte aligned): compiler splits into dword loads
struct __attribute__((packed, aligned(4))) f4u { float x, y, z, w; };

// ---------------- kernel 1: softmax over C for each (b, token) ----------------
__global__ __launch_bounds__(256) void softmax_kernel(const float* __restrict__ preds,
                                                      float* __restrict__ prob) {
    int t = blockIdx.x * blockDim.x + threadIdx.x;   // 0 .. BZ*TOKEN_N-1
    if (t >= BZ * TOKEN_N) return;
    int b = t >> 10, j = t & 1023;
    const float* p = preds + (size_t)b * C_N * TOKEN_N + j;
    float v[C_N];
    float mx = -3.4e38f;
#pragma unroll
    for (int c = 0; c < C_N; ++c) { v[c] = p[(size_t)c * TOKEN_N]; mx = fmaxf(mx, v[c]); }
    float ss = 0.f;
#pragma unroll
    for (int c = 0; c < C_N; ++c) { v[c] = __expf(v[c] - mx); ss += v[c]; }
    float inv = 1.f / ss;
    float* o = prob + (size_t)t * C_N;
#pragma unroll
    for (int c = 0; c < C_N; ++c) o[c] = v[c] * inv;
}

// ---------------- kernel 2: coalesced LDS-staged streaming pass ----------------
// 2048 WGs. WG w: enc = w<1024; matrix mm = (w>>4)&63; row tile i0 = (w&15)*64.
// Stages A[64 rows][64 cols] chunks in LDS (coalesced), thread (i=t&63,q=t>>6)
// accumulates d[c] over its 16 cols/chunk; 4 partials/row reduced via LDS;
// acc[b,i,c] += d[c]/s via fp32 atomics.
__global__ __launch_bounds__(256) void rows2_kernel(const float* __restrict__ attns,
                                                    const float* __restrict__ dattns,
                                                    const float* __restrict__ prob,
                                                    float* __restrict__ acc) {
    const int t  = threadIdx.x;
    const int wg = blockIdx.x;
    const bool enc = wg < 1024;
    const int mm = (wg >> 4) & 63;
    const int i0 = (wg & 15) << 6;
    const int b  = (mm >> 3) & 3;

    const float* base;
    int stride;
    if (enc) {
        base = attns + (size_t)mm * (TOTAL_N * TOTAL_N) + (size_t)(i0 + 1) * TOTAL_N + 1;
        stride = TOTAL_N;
    } else {
        base = dattns + (size_t)mm * (TOKEN_N * TOKEN_N) + (size_t)i0 * TOKEN_N;
        stride = TOKEN_N;
    }

    __shared__ float lds[5632];           // max(64*65 stage, 256*22 reduce) floats

    float d[C_N];
#pragma unroll
    for (int c = 0; c < C_N; ++c) d[c] = 0.f;
    float s = 0.f;

    const float* probB = prob + (size_t)b * (TOKEN_N * C_N);
    const int i = t & 63, q = t >> 6;

    for (int ch = 0; ch < 16; ++ch) {
        // ---- stage 64x64 chunk into LDS (coalesced: 16 lanes x float4 per row) ----
#pragma unroll
        for (int k = 0; k < 4; ++k) {
            int idx = k * 256 + t;
            int r   = idx >> 4;
            int col = (idx & 15) << 2;
            const float* src = base + (size_t)r * stride + ch * 64 + col;
            float x, y, z, w;
            if (enc) { f4u u = *reinterpret_cast<const f4u*>(src); x=u.x; y=u.y; z=u.z; w=u.w; }
            else     { float4 u = *reinterpret_cast<const float4*>(src); x=u.x; y=u.y; z=u.z; w=u.w; }
            float* dst = &lds[r * 65 + col];
            dst[0] = x; dst[1] = y; dst[2] = z; dst[3] = w;
        }
        __syncthreads();
        // ---- compute: thread (i,q) handles cols q*16 .. q*16+15 of row i ----
        const int jbase = ch * 64 + q * 16;
#pragma unroll
        for (int jj = 0; jj < 16; ++jj) {
            float a = lds[i * 65 + q * 16 + jj];
            int off = __builtin_amdgcn_readfirstlane((jbase + jj) * C_N);  // wave-uniform
            const float* pp = probB + off;
            s += a;
#pragma unroll
            for (int c = 0; c < C_N; ++c) d[c] = fmaf(a, pp[c], d[c]);
        }
        __syncthreads();
    }

    // ---- reduce 4 partials per row through LDS ----
    float* red = lds;
#pragma unroll
    for (int c = 0; c < C_N; ++c) red[t * 22 + c] = d[c];
    red[t * 22 + C_N] = s;
    __syncthreads();
    if (t < 64) {
        float dt[C_N], st;
#pragma unroll
        for (int c = 0; c < C_N; ++c)
            dt[c] = red[t * 22 + c] + red[(t + 64) * 22 + c]
                  + red[(t + 128) * 22 + c] + red[(t + 192) * 22 + c];
        st = red[t * 22 + C_N] + red[(t + 64) * 22 + C_N]
           + red[(t + 128) * 22 + C_N] + red[(t + 192) * 22 + C_N];
        float invs = 1.f / st;
        float* ao = acc + ((size_t)b * TOKEN_N + i0 + t) * C_N;
#pragma unroll
        for (int c = 0; c < C_N; ++c) unsafeAtomicAdd(&ao[c], dt[c] * invs);
    }
}

// ---------------- kernel 3: masked L1 loss + ROI count, block-reduced ----------------
__global__ __launch_bounds__(256) void loss_kernel(const float* __restrict__ prob,
                                                   const float* __restrict__ acc,
                                                   const int* __restrict__ roi,
                                                   float* __restrict__ scal) {
    int t = blockIdx.x * 256 + threadIdx.x;          // 0 .. BZ*TOKEN_N-1
    float lossp = 0.f, np = 0.f;
    if (t < BZ * TOKEN_N) {
        int rv = roi[t];
        np = (float)rv;
        const float* a = acc + (size_t)t * C_N;
        const float* p = prob + (size_t)t * C_N;
        float S = 0.f;
#pragma unroll
        for (int c = 0; c < C_N; ++c) S += a[c];
        float invS = 1.f / S;
        float l = 0.f;
#pragma unroll
        for (int c = 0; c < C_N; ++c) l += fabsf(p[c] - a[c] * invS);
        lossp = rv ? l : 0.f;
    }
#pragma unroll
    for (int off = 32; off > 0; off >>= 1) {
        lossp += __shfl_down(lossp, off);
        np    += __shfl_down(np, off);
    }
    __shared__ float redL[4], redN[4];
    int lane = threadIdx.x & 63, wv = threadIdx.x >> 6;
    if (lane == 0) { redL[wv] = lossp; redN[wv] = np; }
    __syncthreads();
    if (threadIdx.x == 0) {
        float L  = redL[0] + redL[1] + redL[2] + redL[3];
        float NN = redN[0] + redN[1] + redN[2] + redN[3];
        unsafeAtomicAdd(&scal[0], L);
        unsafeAtomicAdd(&scal[1], NN);
    }
}

// ---------------- kernel 4: finalize scalar ----------------
__global__ void finalize_kernel(const float* __restrict__ scal, float* __restrict__ out) {
    float loss = scal[0], N = scal[1];
    out[0] = (N > 0.f) ? (loss / N) : loss;   // WEIGHT = 1.0
}

extern "C" void kernel_launch(void* const* d_in, const int* in_sizes, int n_in,
                              void* d_out, int out_size, void* d_ws, size_t ws_size,
                              hipStream_t stream) {
    const float* preds  = (const float*)d_in[0];
    const int*   roi    = (const int*)d_in[3];
    const float* attns  = (const float*)d_in[5];
    const float* dattns = (const float*)d_in[6];

    float* prob = (float*)d_ws;               // 86016 floats
    float* acc  = prob + PROB_ELEMS;          // 86016 floats
    float* scal = acc + PROB_ELEMS;           // 2 floats (loss, N)

    hipMemsetAsync(acc, 0, (PROB_ELEMS + 2) * sizeof(float), stream);

    hipLaunchKernelGGL(softmax_kernel, dim3((BZ * TOKEN_N + 255) / 256), dim3(256), 0, stream,
                       preds, prob);
    hipLaunchKernelGGL(rows2_kernel, dim3(2048), dim3(256), 0, stream,
                       attns, dattns, prob, acc);
    hipLaunchKernelGGL(loss_kernel, dim3((BZ * TOKEN_N + 255) / 256), dim3(256), 0, stream,
                       prob, acc, roi, scal);
    hipLaunchKernelGGL(finalize_kernel, dim3(1), dim3(1), 0, stream,
                       scal, (float*)d_out);
}

// Round 3
// 170.505 us; speedup vs baseline: 3.4125x; 1.7357x over previous
//
#include <hip/hip_runtime.h>
#include <cstdint>
#include <cstddef>

#define C_N     21
#define BZ      4
#define TOKEN_N 1024
#define TOTAL_N 1025
#define PROB_ELEMS (BZ * TOKEN_N * C_N)   // 86016

typedef short  short8  __attribute__((ext_vector_type(8)));
typedef float  f32x16  __attribute__((ext_vector_type(16)));

// fp32 -> bf16 round-to-nearest-even (positive normals; no NaN handling needed here)
static __device__ __forceinline__ unsigned short f2bf(float x) {
    unsigned int u = __float_as_uint(x);
    unsigned int r = (u + 0x7FFFu + ((u >> 16) & 1u)) >> 16;
    return (unsigned short)r;
}

// unaligned-capable float4 (4-byte aligned)
struct __attribute__((packed, aligned(4))) f4u { float x, y, z, w; };

// ---------------- kernel 1: softmax over C for each (b, token) ----------------
__global__ __launch_bounds__(256) void softmax_kernel(const float* __restrict__ preds,
                                                      float* __restrict__ prob) {
    int t = blockIdx.x * blockDim.x + threadIdx.x;   // 0 .. BZ*TOKEN_N-1
    if (t >= BZ * TOKEN_N) return;
    int b = t >> 10, j = t & 1023;
    const float* p = preds + (size_t)b * C_N * TOKEN_N + j;
    float v[C_N];
    float mx = -3.4e38f;
#pragma unroll
    for (int c = 0; c < C_N; ++c) { v[c] = p[(size_t)c * TOKEN_N]; mx = fmaxf(mx, v[c]); }
    float ss = 0.f;
#pragma unroll
    for (int c = 0; c < C_N; ++c) { v[c] = __expf(v[c] - mx); ss += v[c]; }
    float inv = 1.f / ss;
    float* o = prob + (size_t)t * C_N;
#pragma unroll
    for (int c = 0; c < C_N; ++c) o[c] = v[c] * inv;
}

// ---------------- kernel 2: pack prob (+ones col) into MFMA B-fragment layout ----------------
// B[k][n] for v_mfma_f32_32x32x16_bf16: lane l holds n = l&31, k = 8*(l>>5)+e (e=0..7).
// bp[((b*64 + kk)*64 + lane)] = uint4 of 8 bf16. n==21 -> 1.0 (row-sum column), n>21 -> 0.
__global__ __launch_bounds__(256) void bpack_kernel(const float* __restrict__ prob,
                                                    uint4* __restrict__ bp) {
    int idx = blockIdx.x * 256 + threadIdx.x;        // 0 .. 16383
    if (idx >= BZ * 64 * 64) return;
    int lane = idx & 63;
    int kk   = (idx >> 6) & 63;
    int b    = idx >> 12;
    int col  = lane & 31, grp = lane >> 5;
    int k0   = kk * 16 + grp * 8;
    unsigned short h[8];
#pragma unroll
    for (int e = 0; e < 8; ++e) {
        float v;
        if (col < C_N)       v = prob[((size_t)b * TOKEN_N + (k0 + e)) * C_N + col];
        else if (col == C_N) v = 1.0f;
        else                 v = 0.0f;
        h[e] = f2bf(v);
    }
    uint4 o;
    o.x = h[0] | ((unsigned)h[1] << 16);
    o.y = h[2] | ((unsigned)h[3] << 16);
    o.z = h[4] | ((unsigned)h[5] << 16);
    o.w = h[6] | ((unsigned)h[7] << 16);
    bp[idx] = o;
}

// ---------------- kernel 3: MFMA streaming pass ----------------
// 4096 waves; wave wid: matrix m = wid>>5 (0..127), row tile i0 = (wid&31)*32.
// A-frag: lane l reads 8 consecutive fp32 of row (i0 + (l&31)) at k = kk*16 + 8*(l>>5),
// cvt to bf16. B-frag: one coalesced dwordx4 from bp. 64 MFMAs accumulate D[32x22]:
// cols 0..20 = d[c], col 21 = s. Then acc[b,i,c] += d/s via fp32 atomics.
__global__ __launch_bounds__(256) void rows3_kernel(const float* __restrict__ attns,
                                                    const float* __restrict__ dattns,
                                                    const uint4* __restrict__ bp,
                                                    float* __restrict__ acc) {
    const int tid  = threadIdx.x;
    const int lane = tid & 63;
    const int wid  = blockIdx.x * 4 + (tid >> 6);   // 0..4095
    const int m    = wid >> 5;                       // 0..127
    const int i0   = (wid & 31) << 5;                // row base
    const int col  = lane & 31;
    const int grp  = lane >> 5;

    int b;
    const float* rowp;
    if (m < 64) {            // enc: attns[l,b,h, 1+i, 1+j]
        b = (m >> 3) & 3;
        rowp = attns + (size_t)m * ((size_t)TOTAL_N * TOTAL_N)
                     + (size_t)(i0 + col + 1) * TOTAL_N + 1;
    } else {                 // dec
        int md = m - 64;
        b = (md >> 3) & 3;
        rowp = dattns + (size_t)md * ((size_t)TOKEN_N * TOKEN_N)
                      + (size_t)(i0 + col) * TOKEN_N;
    }
    rowp += grp * 8;         // k-subgroup offset within each K-step
    const uint4* bpp = bp + (size_t)b * (64 * 64) + lane;

    f32x16 C;
#pragma unroll
    for (int r = 0; r < 16; ++r) C[r] = 0.f;

#pragma unroll 4
    for (int kk = 0; kk < 64; ++kk) {
        const float* ap = rowp + kk * 16;
        f4u a0 = *reinterpret_cast<const f4u*>(ap);
        f4u a1 = *reinterpret_cast<const f4u*>(ap + 4);
        uint4 bw = bpp[(size_t)kk * 64];

        unsigned int w0 = (unsigned)f2bf(a0.x) | ((unsigned)f2bf(a0.y) << 16);
        unsigned int w1 = (unsigned)f2bf(a0.z) | ((unsigned)f2bf(a0.w) << 16);
        unsigned int w2 = (unsigned)f2bf(a1.x) | ((unsigned)f2bf(a1.y) << 16);
        unsigned int w3 = (unsigned)f2bf(a1.z) | ((unsigned)f2bf(a1.w) << 16);
        uint4 aw; aw.x = w0; aw.y = w1; aw.z = w2; aw.w = w3;

        short8 af = __builtin_bit_cast(short8, aw);
        short8 bf = __builtin_bit_cast(short8, bw);
        C = __builtin_amdgcn_mfma_f32_32x32x16_bf16(af, bf, C, 0, 0, 0);
    }

    // D layout (HW-verified): col = lane&31, row = (reg&3) + 8*(reg>>2) + 4*(lane>>5)
#pragma unroll
    for (int r = 0; r < 16; ++r) {
        float sv  = __shfl(C[r], 21 + (lane & 32));   // col-21 lane of this group
        float val = C[r] * (1.f / sv);
        int rloc  = (r & 3) + 8 * (r >> 2) + 4 * grp;
        if (col < C_N)
            unsafeAtomicAdd(&acc[((size_t)b * TOKEN_N + i0 + rloc) * C_N + col], val);
    }
}

// ---------------- kernel 4: masked L1 loss + ROI count, block-reduced ----------------
__global__ __launch_bounds__(256) void loss_kernel(const float* __restrict__ prob,
                                                   const float* __restrict__ acc,
                                                   const int* __restrict__ roi,
                                                   float* __restrict__ scal) {
    int t = blockIdx.x * 256 + threadIdx.x;          // 0 .. BZ*TOKEN_N-1
    float lossp = 0.f, np = 0.f;
    if (t < BZ * TOKEN_N) {
        int rv = roi[t];
        np = (float)rv;
        const float* a = acc + (size_t)t * C_N;
        const float* p = prob + (size_t)t * C_N;
        float S = 0.f;
#pragma unroll
        for (int c = 0; c < C_N; ++c) S += a[c];
        float invS = 1.f / S;
        float l = 0.f;
#pragma unroll
        for (int c = 0; c < C_N; ++c) l += fabsf(p[c] - a[c] * invS);
        lossp = rv ? l : 0.f;
    }
#pragma unroll
    for (int off = 32; off > 0; off >>= 1) {
        lossp += __shfl_down(lossp, off);
        np    += __shfl_down(np, off);
    }
    __shared__ float redL[4], redN[4];
    int lane = threadIdx.x & 63, wv = threadIdx.x >> 6;
    if (lane == 0) { redL[wv] = lossp; redN[wv] = np; }
    __syncthreads();
    if (threadIdx.x == 0) {
        float L  = redL[0] + redL[1] + redL[2] + redL[3];
        float NN = redN[0] + redN[1] + redN[2] + redN[3];
        unsafeAtomicAdd(&scal[0], L);
        unsafeAtomicAdd(&scal[1], NN);
    }
}

// ---------------- kernel 5: finalize scalar ----------------
__global__ void finalize_kernel(const float* __restrict__ scal, float* __restrict__ out) {
    float loss = scal[0], N = scal[1];
    out[0] = (N > 0.f) ? (loss / N) : loss;   // WEIGHT = 1.0
}

extern "C" void kernel_launch(void* const* d_in, const int* in_sizes, int n_in,
                              void* d_out, int out_size, void* d_ws, size_t ws_size,
                              hipStream_t stream) {
    const float* preds  = (const float*)d_in[0];
    const int*   roi    = (const int*)d_in[3];
    const float* attns  = (const float*)d_in[5];
    const float* dattns = (const float*)d_in[6];

    float* prob = (float*)d_ws;               // 86016 floats
    float* acc  = prob + PROB_ELEMS;          // 86016 floats
    float* scal = acc + PROB_ELEMS;           // 2 floats (loss, N)
    // B-pack buffer, 16B-aligned: 4 b * 64 kk * 64 lanes * 16 B = 256 KB
    uint4* bpack = (uint4*)((char*)d_ws + ((PROB_ELEMS * 2 + 2) * sizeof(float) + 15 & ~(size_t)15));

    hipMemsetAsync(acc, 0, (PROB_ELEMS + 2) * sizeof(float), stream);

    hipLaunchKernelGGL(softmax_kernel, dim3((BZ * TOKEN_N + 255) / 256), dim3(256), 0, stream,
                       preds, prob);
    hipLaunchKernelGGL(bpack_kernel, dim3(64), dim3(256), 0, stream,
                       prob, bpack);
    hipLaunchKernelGGL(rows3_kernel, dim3(1024), dim3(256), 0, stream,
                       attns, dattns, bpack, acc);
    hipLaunchKernelGGL(loss_kernel, dim3((BZ * TOKEN_N + 255) / 256), dim3(256), 0, stream,
                       prob, acc, roi, scal);
    hipLaunchKernelGGL(finalize_kernel, dim3(1), dim3(1), 0, stream,
                       scal, (float*)d_out);
}

// Round 4
// 141.342 us; speedup vs baseline: 4.1166x; 1.2063x over previous
//
#include <hip/hip_runtime.h>
#include <cstdint>
#include <cstddef>

#define C_N     21
#define BZ      4
#define TOKEN_N 1024
#define TOTAL_N 1025
#define PROB_ELEMS (BZ * TOKEN_N * C_N)   // 86016

typedef short  short8 __attribute__((ext_vector_type(8)));
typedef float  f32x4  __attribute__((ext_vector_type(4)));

// fp32 -> bf16 round-to-nearest-even (positive normals only here)
static __device__ __forceinline__ unsigned short f2bf(float x) {
    unsigned int u = __float_as_uint(x);
    unsigned int r = (u + 0x7FFFu + ((u >> 16) & 1u)) >> 16;
    return (unsigned short)r;
}

// unaligned-capable float4 (4-byte aligned)
struct __attribute__((packed, aligned(4))) f4u { float x, y, z, w; };

// ---------------- kernel 1: softmax over C for each (b, token) ----------------
__global__ __launch_bounds__(256) void softmax_kernel(const float* __restrict__ preds,
                                                      float* __restrict__ prob) {
    int t = blockIdx.x * blockDim.x + threadIdx.x;   // 0 .. BZ*TOKEN_N-1
    if (t >= BZ * TOKEN_N) return;
    int b = t >> 10, j = t & 1023;
    const float* p = preds + (size_t)b * C_N * TOKEN_N + j;
    float v[C_N];
    float mx = -3.4e38f;
#pragma unroll
    for (int c = 0; c < C_N; ++c) { v[c] = p[(size_t)c * TOKEN_N]; mx = fmaxf(mx, v[c]); }
    float ss = 0.f;
#pragma unroll
    for (int c = 0; c < C_N; ++c) { v[c] = __expf(v[c] - mx); ss += v[c]; }
    float inv = 1.f / ss;
    float* o = prob + (size_t)t * C_N;
#pragma unroll
    for (int c = 0; c < C_N; ++c) o[c] = v[c] * inv;
}

// ---------------- kernel 2: pack prob (+ones col) into 16x16x32 B-fragments ----------------
// B[k][n]: lane l holds n = (l&15) + nt*16, k = kk*32 + (l>>4)*8 + e (e=0..7).
// Element index: b*4096 + kk*128 + nt*64 + lane. nt=1 col 21 -> 1.0 (row-sum), >21 -> 0.
__global__ __launch_bounds__(256) void bpack2_kernel(const float* __restrict__ prob,
                                                     uint4* __restrict__ bp) {
    int idx = blockIdx.x * 256 + threadIdx.x;        // 0 .. 16383
    if (idx >= BZ * 32 * 2 * 64) return;
    int lane = idx & 63;
    int nt   = (idx >> 6) & 1;
    int kk   = (idx >> 7) & 31;
    int b    = idx >> 12;
    int n    = (lane & 15) + nt * 16;
    int k0   = kk * 32 + ((lane >> 4) << 3);
    unsigned short h[8];
#pragma unroll
    for (int e = 0; e < 8; ++e) {
        float v;
        if (n < C_N)       v = prob[((size_t)b * TOKEN_N + (k0 + e)) * C_N + n];
        else if (n == C_N) v = 1.0f;
        else               v = 0.0f;
        h[e] = f2bf(v);
    }
    uint4 o;
    o.x = h[0] | ((unsigned)h[1] << 16);
    o.y = h[2] | ((unsigned)h[3] << 16);
    o.z = h[4] | ((unsigned)h[5] << 16);
    o.w = h[6] | ((unsigned)h[7] << 16);
    bp[idx] = o;
}

// ---------------- kernel 3: 16x16x32 MFMA streaming pass ----------------
template<bool ENC>
__device__ __forceinline__ void rows_body(const float* __restrict__ base, int mm, int lane,
                                          int i0, const uint4* __restrict__ bp,
                                          float* __restrict__ acc) {
    const int b   = (mm >> 3) & 3;
    const int row = i0 + (lane & 15);
    const int kg8 = (lane >> 4) << 3;
    const float* rowp;
    if constexpr (ENC)
        rowp = base + (size_t)mm * ((size_t)TOTAL_N * TOTAL_N) + (size_t)(row + 1) * TOTAL_N + 1 + kg8;
    else
        rowp = base + (size_t)mm * ((size_t)TOKEN_N * TOKEN_N) + (size_t)row * TOKEN_N + kg8;
    const uint4* bpp = bp + (size_t)b * 4096 + lane;

    f32x4 c0 = {0.f, 0.f, 0.f, 0.f};
    f32x4 c1 = {0.f, 0.f, 0.f, 0.f};

    float a00, a01, a02, a03, a04, a05, a06, a07;
    float a10, a11, a12, a13, a14, a15, a16, a17;
    uint4 B00, B01, B10, B11;

#define LOADA(s, kk) do { const float* p_ = rowp + (kk) * 32;                         \
    if constexpr (ENC) {                                                              \
        f4u u_ = *reinterpret_cast<const f4u*>(p_);                                   \
        f4u v_ = *reinterpret_cast<const f4u*>(p_ + 4);                               \
        a##s##0 = u_.x; a##s##1 = u_.y; a##s##2 = u_.z; a##s##3 = u_.w;               \
        a##s##4 = v_.x; a##s##5 = v_.y; a##s##6 = v_.z; a##s##7 = v_.w;               \
    } else {                                                                          \
        float4 u_ = *reinterpret_cast<const float4*>(p_);                             \
        float4 v_ = *reinterpret_cast<const float4*>(p_ + 4);                         \
        a##s##0 = u_.x; a##s##1 = u_.y; a##s##2 = u_.z; a##s##3 = u_.w;               \
        a##s##4 = v_.x; a##s##5 = v_.y; a##s##6 = v_.z; a##s##7 = v_.w;               \
    } } while (0)

#define COMPUTE(s, BB0, BB1) do {                                                     \
    unsigned w0_ = (unsigned)f2bf(a##s##0) | ((unsigned)f2bf(a##s##1) << 16);         \
    unsigned w1_ = (unsigned)f2bf(a##s##2) | ((unsigned)f2bf(a##s##3) << 16);         \
    unsigned w2_ = (unsigned)f2bf(a##s##4) | ((unsigned)f2bf(a##s##5) << 16);         \
    unsigned w3_ = (unsigned)f2bf(a##s##6) | ((unsigned)f2bf(a##s##7) << 16);         \
    uint4 aw_; aw_.x = w0_; aw_.y = w1_; aw_.z = w2_; aw_.w = w3_;                    \
    short8 af_ = __builtin_bit_cast(short8, aw_);                                     \
    c0 = __builtin_amdgcn_mfma_f32_16x16x32_bf16(af_, __builtin_bit_cast(short8, BB0), c0, 0, 0, 0); \
    c1 = __builtin_amdgcn_mfma_f32_16x16x32_bf16(af_, __builtin_bit_cast(short8, BB1), c1, 0, 0, 0); \
    } while (0)

    LOADA(0, 0); B00 = bpp[0];   B01 = bpp[64];
    LOADA(1, 1); B10 = bpp[128]; B11 = bpp[192];
    for (int kk = 0; kk < 30; kk += 2) {
        COMPUTE(0, B00, B01);
        LOADA(0, kk + 2); B00 = bpp[(kk + 2) * 128]; B01 = bpp[(kk + 2) * 128 + 64];
        COMPUTE(1, B10, B11);
        LOADA(1, kk + 3); B10 = bpp[(kk + 3) * 128]; B11 = bpp[(kk + 3) * 128 + 64];
    }
    COMPUTE(0, B00, B01);
    COMPUTE(1, B10, B11);
#undef LOADA
#undef COMPUTE

    // D layout (HW-verified m89): col = lane&15, row = (lane>>4)*4 + reg
    const int grp = lane >> 4, coln = lane & 15;
#pragma unroll
    for (int r = 0; r < 4; ++r) {
        float sv  = __shfl(c1[r], (lane & 48) + 5);   // n==21 lane of this row group
        float inv = 1.0f / sv;
        int i = i0 + grp * 4 + r;
        float* ao = acc + ((size_t)b * TOKEN_N + i) * C_N;
        unsafeAtomicAdd(&ao[coln], c0[r] * inv);
        if (coln < C_N - 16) unsafeAtomicAdd(&ao[16 + coln], c1[r] * inv);
    }
}

__global__ __launch_bounds__(256) void rows4_kernel(const float* __restrict__ attns,
                                                    const float* __restrict__ dattns,
                                                    const uint4* __restrict__ bp,
                                                    float* __restrict__ acc) {
    const int lane = threadIdx.x & 63;
    const int wid  = blockIdx.x * 4 + (threadIdx.x >> 6);  // 0..8191
    const int m    = wid >> 6;                              // 0..127 (block-uniform)
    const int i0   = (wid & 63) << 4;                       // row base (16 rows/wave)
    if (m < 64) rows_body<true >(attns,  m,      lane, i0, bp, acc);
    else        rows_body<false>(dattns, m - 64, lane, i0, bp, acc);
}

// ---------------- kernel 4: masked L1 loss + ROI count, block-reduced ----------------
__global__ __launch_bounds__(256) void loss_kernel(const float* __restrict__ prob,
                                                   const float* __restrict__ acc,
                                                   const int* __restrict__ roi,
                                                   float* __restrict__ scal) {
    int t = blockIdx.x * 256 + threadIdx.x;          // 0 .. BZ*TOKEN_N-1
    float lossp = 0.f, np = 0.f;
    if (t < BZ * TOKEN_N) {
        int rv = roi[t];
        np = (float)rv;
        const float* a = acc + (size_t)t * C_N;
        const float* p = prob + (size_t)t * C_N;
        float S = 0.f;
#pragma unroll
        for (int c = 0; c < C_N; ++c) S += a[c];
        float invS = 1.f / S;
        float l = 0.f;
#pragma unroll
        for (int c = 0; c < C_N; ++c) l += fabsf(p[c] - a[c] * invS);
        lossp = rv ? l : 0.f;
    }
#pragma unroll
    for (int off = 32; off > 0; off >>= 1) {
        lossp += __shfl_down(lossp, off);
        np    += __shfl_down(np, off);
    }
    __shared__ float redL[4], redN[4];
    int lane = threadIdx.x & 63, wv = threadIdx.x >> 6;
    if (lane == 0) { redL[wv] = lossp; redN[wv] = np; }
    __syncthreads();
    if (threadIdx.x == 0) {
        float L  = redL[0] + redL[1] + redL[2] + redL[3];
        float NN = redN[0] + redN[1] + redN[2] + redN[3];
        unsafeAtomicAdd(&scal[0], L);
        unsafeAtomicAdd(&scal[1], NN);
    }
}

// ---------------- kernel 5: finalize scalar ----------------
__global__ void finalize_kernel(const float* __restrict__ scal, float* __restrict__ out) {
    float loss = scal[0], N = scal[1];
    out[0] = (N > 0.f) ? (loss / N) : loss;   // WEIGHT = 1.0
}

extern "C" void kernel_launch(void* const* d_in, const int* in_sizes, int n_in,
                              void* d_out, int out_size, void* d_ws, size_t ws_size,
                              hipStream_t stream) {
    const float* preds  = (const float*)d_in[0];
    const int*   roi    = (const int*)d_in[3];
    const float* attns  = (const float*)d_in[5];
    const float* dattns = (const float*)d_in[6];

    float* prob = (float*)d_ws;               // 86016 floats
    float* acc  = prob + PROB_ELEMS;          // 86016 floats
    float* scal = acc + PROB_ELEMS;           // 2 floats (loss, N)
    // B-pack buffer, 16B-aligned: 4 b * 32 kk * 2 nt * 64 lanes * 16 B = 256 KB
    uint4* bpack = (uint4*)((char*)d_ws + ((PROB_ELEMS * 2 + 2) * sizeof(float) + 15 & ~(size_t)15));

    hipMemsetAsync(acc, 0, (PROB_ELEMS + 2) * sizeof(float), stream);

    hipLaunchKernelGGL(softmax_kernel, dim3((BZ * TOKEN_N + 255) / 256), dim3(256), 0, stream,
                       preds, prob);
    hipLaunchKernelGGL(bpack2_kernel, dim3(64), dim3(256), 0, stream,
                       prob, bpack);
    hipLaunchKernelGGL(rows4_kernel, dim3(2048), dim3(256), 0, stream,
                       attns, dattns, bpack, acc);
    hipLaunchKernelGGL(loss_kernel, dim3((BZ * TOKEN_N + 255) / 256), dim3(256), 0, stream,
                       prob, acc, roi, scal);
    hipLaunchKernelGGL(finalize_kernel, dim3(1), dim3(1), 0, stream,
                       scal, (float*)d_out);
}

// Round 5
// 129.908 us; speedup vs baseline: 4.4789x; 1.0880x over previous
//
#include <hip/hip_runtime.h>
#include <cstdint>
#include <cstddef>

#define C_N     21
#define BZ      4
#define TOKEN_N 1024
#define TOTAL_N 1025
#define PROB_ELEMS (BZ * TOKEN_N * C_N)   // 86016
#define ENC_TOT  (2u * 4u * 8u * 1050625u)  // 67240000 floats in attns

typedef short  short8 __attribute__((ext_vector_type(8)));
typedef float  f32x4  __attribute__((ext_vector_type(4)));

// fp32 -> bf16 round-to-nearest-even (non-negative normals only here)
static __device__ __forceinline__ unsigned int f2bf(float x) {
    unsigned int u = __float_as_uint(x);
    return (u + 0x7FFFu + ((u >> 16) & 1u)) >> 16;
}

// ---------------- kernel 1: softmax over C for each (b, token) ----------------
__global__ __launch_bounds__(256) void softmax_kernel(const float* __restrict__ preds,
                                                      float* __restrict__ prob) {
    int t = blockIdx.x * blockDim.x + threadIdx.x;   // 0 .. BZ*TOKEN_N-1
    if (t >= BZ * TOKEN_N) return;
    int b = t >> 10, j = t & 1023;
    const float* p = preds + (size_t)b * C_N * TOKEN_N + j;
    float v[C_N];
    float mx = -3.4e38f;
#pragma unroll
    for (int c = 0; c < C_N; ++c) { v[c] = p[(size_t)c * TOKEN_N]; mx = fmaxf(mx, v[c]); }
    float ss = 0.f;
#pragma unroll
    for (int c = 0; c < C_N; ++c) { v[c] = __expf(v[c] - mx); ss += v[c]; }
    float inv = 1.f / ss;
    float* o = prob + (size_t)t * C_N;
#pragma unroll
    for (int c = 0; c < C_N; ++c) o[c] = v[c] * inv;
}

// ---------------- kernel 2: pack prob (+ones col) into 16x16x32 B-fragments ----------------
// B[k][n]: lane l holds n = (l&15) + nt*16, k = kk*32 + (l>>4)*8 + e (e=0..7).
// Element index: b*4096 + kk*128 + nt*64 + lane. n==21 -> 1.0 (row-sum), >21 -> 0.
__global__ __launch_bounds__(256) void bpack2_kernel(const float* __restrict__ prob,
                                                     uint4* __restrict__ bp) {
    int idx = blockIdx.x * 256 + threadIdx.x;        // 0 .. 16383
    if (idx >= BZ * 32 * 2 * 64) return;
    int lane = idx & 63;
    int nt   = (idx >> 6) & 1;
    int kk   = (idx >> 7) & 31;
    int b    = idx >> 12;
    int n    = (lane & 15) + nt * 16;
    int k0   = kk * 32 + ((lane >> 4) << 3);
    unsigned int h[8];
#pragma unroll
    for (int e = 0; e < 8; ++e) {
        float v;
        if (n < C_N)       v = prob[((size_t)b * TOKEN_N + (k0 + e)) * C_N + n];
        else if (n == C_N) v = 1.0f;
        else               v = 0.0f;
        h[e] = f2bf(v);
    }
    uint4 o;
    o.x = h[0] | (h[1] << 16);
    o.y = h[2] | (h[3] << 16);
    o.z = h[4] | (h[5] << 16);
    o.w = h[6] | (h[7] << 16);
    bp[idx] = o;
}

// ---------------- kernel 3: LDS-staged 16x16x32 MFMA streaming pass ----------------
// Each WAVE (independent, no barriers) owns 16 rows x K=1024 of one matrix.
// Per 64-col chunk: stage rows into private LDS with contiguous float4 loads
// (full 64B lines), read MFMA fragments from LDS, 1-chunk-deep prefetch.
template<bool ENC>
__device__ __forceinline__ void rows_body(const float* __restrict__ base, int mm, int lane,
                                          int i0, const uint4* __restrict__ bp,
                                          float* __restrict__ acc, float* __restrict__ ldsw) {
    constexpr int UPR   = ENC ? 17 : 16;   // 16B units per row window
    constexpr int RS    = ENC ? 68 : 64;   // floats per row window
    constexpr int NSLOT = ENC ? 5 : 4;     // staging issues (64 units each)
    const int b = (mm >> 3) & 3;

    // ---- per-lane staging source pointers (chunk 0), 16B-aligned ----
    const float* gs[5];
#pragma unroll
    for (int s = 0; s < NSLOT; ++s) {
        int t = (ENC && s == 4) ? (256 + (lane & 15)) : (s * 64 + lane);
        int row = t / UPR;
        int u   = t - row * UPR;
        size_t gidx;
        if constexpr (ENC) {
            size_t start = (size_t)mm * 1050625u + (size_t)(1 + i0 + row) * 1025u + 1u;
            int delta = (int)(start & 3);
            gidx = start - delta + (size_t)u * 4;
            if (s == 4 && gidx > (size_t)(ENC_TOT - 4)) gidx = ENC_TOT - 4;  // tail clamp (delta=0 row; bytes unused)
        } else {
            gidx = (size_t)mm * 1048576u + (size_t)(i0 + row) * 1024u + (size_t)u * 4;
        }
        gs[s] = base + gidx;
    }

    float4 G[5];
    auto LOADG = [&](int ch) {
#pragma unroll
        for (int s = 0; s < NSLOT; ++s)
            G[s] = *reinterpret_cast<const float4*>(gs[s] + ch * 64);
    };
    auto WRITEG = [&](int buf) {
        float* d = ldsw + buf * 1088;
#pragma unroll
        for (int s = 0; s < NSLOT; ++s) {
            int t = (ENC && s == 4) ? (256 + (lane & 15)) : (s * 64 + lane);
            *reinterpret_cast<float4*>(d + (size_t)t * 4) = G[s];
        }
    };

    const uint4* bpp = bp + (size_t)b * 4096 + lane;
    uint4 B0, B1, B2, B3, N0, N1, N2, N3;
    auto LOADBN = [&](int ch) {
        N0 = bpp[ch * 256];       N1 = bpp[ch * 256 + 64];
        N2 = bpp[ch * 256 + 128]; N3 = bpp[ch * 256 + 192];
    };

    // ---- fragment read base in LDS window ----
    const int r = lane & 15, kg = lane >> 4;
    int fragbase;
    if constexpr (ENC) fragbase = r * RS + ((mm + i0 + r + 2) & 3) + kg * 8;
    else               fragbase = r * RS + kg * 8;

    f32x4 c0 = {0.f, 0.f, 0.f, 0.f};
    f32x4 c1 = {0.f, 0.f, 0.f, 0.f};
    auto KSTEP = [&](const float* lf, int j0, uint4 bb0, uint4 bb1) {
        float a0, a1, a2, a3, a4, a5, a6, a7;
        if constexpr (ENC) {
            const float* p = lf + fragbase + j0;
            a0 = p[0]; a1 = p[1]; a2 = p[2]; a3 = p[3];
            a4 = p[4]; a5 = p[5]; a6 = p[6]; a7 = p[7];
        } else {
            float4 lo = *reinterpret_cast<const float4*>(lf + fragbase + j0);
            float4 hi = *reinterpret_cast<const float4*>(lf + fragbase + j0 + 4);
            a0 = lo.x; a1 = lo.y; a2 = lo.z; a3 = lo.w;
            a4 = hi.x; a5 = hi.y; a6 = hi.z; a7 = hi.w;
        }
        uint4 aw;
        aw.x = f2bf(a0) | (f2bf(a1) << 16);
        aw.y = f2bf(a2) | (f2bf(a3) << 16);
        aw.z = f2bf(a4) | (f2bf(a5) << 16);
        aw.w = f2bf(a6) | (f2bf(a7) << 16);
        short8 af = __builtin_bit_cast(short8, aw);
        c0 = __builtin_amdgcn_mfma_f32_16x16x32_bf16(af, __builtin_bit_cast(short8, bb0), c0, 0, 0, 0);
        c1 = __builtin_amdgcn_mfma_f32_16x16x32_bf16(af, __builtin_bit_cast(short8, bb1), c1, 0, 0, 0);
    };

    // ---- prologue ----
    LOADG(0); LOADBN(0);
    B0 = N0; B1 = N1; B2 = N2; B3 = N3;
    WRITEG(0);                       // waits G(0)
    LOADG(1); LOADBN(1);

    // ---- main pipeline: compute(ch) from LDS, then write prefetched ch+1 ----
#pragma unroll 2
    for (int ch = 0; ch < 14; ++ch) {
        const int cur = ch & 1;
        const float* lf = ldsw + cur * 1088;
        KSTEP(lf, 0,  B0, B1);
        KSTEP(lf, 32, B2, B3);
        WRITEG(cur ^ 1);             // vmcnt wait for G(ch+1) lands after compute
        B0 = N0; B1 = N1; B2 = N2; B3 = N3;
        LOADG(ch + 2); LOADBN(ch + 2);
    }
    {   // ch = 14
        const float* lf = ldsw + 0 * 1088;
        KSTEP(lf, 0,  B0, B1);
        KSTEP(lf, 32, B2, B3);
        WRITEG(1);
        B0 = N0; B1 = N1; B2 = N2; B3 = N3;
    }
    {   // ch = 15
        const float* lf = ldsw + 1 * 1088;
        KSTEP(lf, 0,  B0, B1);
        KSTEP(lf, 32, B2, B3);
    }

    // ---- epilogue: D layout (m89): col = lane&15, row = (lane>>4)*4 + reg ----
#pragma unroll
    for (int rr = 0; rr < 4; ++rr) {
        float sv  = __shfl(c1[rr], (lane & 48) + 5);   // n==21 lane of this row group
        float inv = 1.0f / sv;
        int i = i0 + kg * 4 + rr;
        float* ao = acc + ((size_t)b * TOKEN_N + i) * C_N;
        unsafeAtomicAdd(&ao[r], c0[rr] * inv);
        if (r < C_N - 16) unsafeAtomicAdd(&ao[16 + r], c1[rr] * inv);
    }
}

__global__ __launch_bounds__(256) void rows5_kernel(const float* __restrict__ attns,
                                                    const float* __restrict__ dattns,
                                                    const uint4* __restrict__ bp,
                                                    float* __restrict__ acc) {
    __shared__ __align__(16) float lds[8704];          // 4 waves x 2 bufs x 1088 floats
    const int lane = threadIdx.x & 63;
    const int wv   = threadIdx.x >> 6;
    float* ldsw = lds + wv * 2176;
    const int wid  = blockIdx.x * 4 + wv;              // 0..8191
    const int m    = wid >> 6;                          // 0..127 (block-uniform)
    const int i0   = (wid & 63) << 4;                   // row base (16 rows/wave)
    if (m < 64) rows_body<true >(attns,  m,      lane, i0, bp, acc, ldsw);
    else        rows_body<false>(dattns, m - 64, lane, i0, bp, acc, ldsw);
}

// ---------------- kernel 4: masked L1 loss + ROI count, block-reduced ----------------
__global__ __launch_bounds__(256) void loss_kernel(const float* __restrict__ prob,
                                                   const float* __restrict__ acc,
                                                   const int* __restrict__ roi,
                                                   float* __restrict__ scal) {
    int t = blockIdx.x * 256 + threadIdx.x;          // 0 .. BZ*TOKEN_N-1
    float lossp = 0.f, np = 0.f;
    if (t < BZ * TOKEN_N) {
        int rv = roi[t];
        np = (float)rv;
        const float* a = acc + (size_t)t * C_N;
        const float* p = prob + (size_t)t * C_N;
        float S = 0.f;
#pragma unroll
        for (int c = 0; c < C_N; ++c) S += a[c];
        float invS = 1.f / S;
        float l = 0.f;
#pragma unroll
        for (int c = 0; c < C_N; ++c) l += fabsf(p[c] - a[c] * invS);
        lossp = rv ? l : 0.f;
    }
#pragma unroll
    for (int off = 32; off > 0; off >>= 1) {
        lossp += __shfl_down(lossp, off);
        np    += __shfl_down(np, off);
    }
    __shared__ float redL[4], redN[4];
    int lane = threadIdx.x & 63, wv = threadIdx.x >> 6;
    if (lane == 0) { redL[wv] = lossp; redN[wv] = np; }
    __syncthreads();
    if (threadIdx.x == 0) {
        float L  = redL[0] + redL[1] + redL[2] + redL[3];
        float NN = redN[0] + redN[1] + redN[2] + redN[3];
        unsafeAtomicAdd(&scal[0], L);
        unsafeAtomicAdd(&scal[1], NN);
    }
}

// ---------------- kernel 5: finalize scalar ----------------
__global__ void finalize_kernel(const float* __restrict__ scal, float* __restrict__ out) {
    float loss = scal[0], N = scal[1];
    out[0] = (N > 0.f) ? (loss / N) : loss;   // WEIGHT = 1.0
}

extern "C" void kernel_launch(void* const* d_in, const int* in_sizes, int n_in,
                              void* d_out, int out_size, void* d_ws, size_t ws_size,
                              hipStream_t stream) {
    const float* preds  = (const float*)d_in[0];
    const int*   roi    = (const int*)d_in[3];
    const float* attns  = (const float*)d_in[5];
    const float* dattns = (const float*)d_in[6];

    float* prob = (float*)d_ws;               // 86016 floats
    float* acc  = prob + PROB_ELEMS;          // 86016 floats
    float* scal = acc + PROB_ELEMS;           // 2 floats (loss, N)
    // B-pack buffer, 16B-aligned: 4 b * 32 kk * 2 nt * 64 lanes * 16 B = 256 KB
    uint4* bpack = (uint4*)((char*)d_ws + ((PROB_ELEMS * 2 + 2) * sizeof(float) + 15 & ~(size_t)15));

    hipMemsetAsync(acc, 0, (PROB_ELEMS + 2) * sizeof(float), stream);

    hipLaunchKernelGGL(softmax_kernel, dim3((BZ * TOKEN_N + 255) / 256), dim3(256), 0, stream,
                       preds, prob);
    hipLaunchKernelGGL(bpack2_kernel, dim3(64), dim3(256), 0, stream,
                       prob, bpack);
    hipLaunchKernelGGL(rows5_kernel, dim3(2048), dim3(256), 0, stream,
                       attns, dattns, bpack, acc);
    hipLaunchKernelGGL(loss_kernel, dim3((BZ * TOKEN_N + 255) / 256), dim3(256), 0, stream,
                       prob, acc, roi, scal);
    hipLaunchKernelGGL(finalize_kernel, dim3(1), dim3(1), 0, stream,
                       scal, (float*)d_out);
}

// Round 6
// 129.680 us; speedup vs baseline: 4.4868x; 1.0018x over previous
//
#include <hip/hip_runtime.h>
#include <cstdint>
#include <cstddef>

#define C_N     21
#define BZ      4
#define TOKEN_N 1024
#define TOTAL_N 1025
#define PROB_ELEMS (BZ * TOKEN_N * C_N)   // 86016
#define ENC_TOT  67240000u                // floats in attns (2*4*8*1025*1025)

typedef short  short8 __attribute__((ext_vector_type(8)));
typedef float  f32x4  __attribute__((ext_vector_type(4)));

// fp32 -> bf16 round-to-nearest-even (non-negative normals only here)
static __device__ __forceinline__ unsigned int f2bf(float x) {
    unsigned int u = __float_as_uint(x);
    return (u + 0x7FFFu + ((u >> 16) & 1u)) >> 16;
}

// ---------------- kernel 1: softmax over C for each (b, token) ----------------
__global__ __launch_bounds__(256) void softmax_kernel(const float* __restrict__ preds,
                                                      float* __restrict__ prob) {
    int t = blockIdx.x * blockDim.x + threadIdx.x;   // 0 .. BZ*TOKEN_N-1
    if (t >= BZ * TOKEN_N) return;
    int b = t >> 10, j = t & 1023;
    const float* p = preds + (size_t)b * C_N * TOKEN_N + j;
    float v[C_N];
    float mx = -3.4e38f;
#pragma unroll
    for (int c = 0; c < C_N; ++c) { v[c] = p[(size_t)c * TOKEN_N]; mx = fmaxf(mx, v[c]); }
    float ss = 0.f;
#pragma unroll
    for (int c = 0; c < C_N; ++c) { v[c] = __expf(v[c] - mx); ss += v[c]; }
    float inv = 1.f / ss;
    float* o = prob + (size_t)t * C_N;
#pragma unroll
    for (int c = 0; c < C_N; ++c) o[c] = v[c] * inv;
}

// ---------------- kernel 2: pack prob (+ones col) into 16x16x32 B-fragments ----------------
// B[k][n]: lane l holds n = (l&15) + nt*16, k = kk*32 + (l>>4)*8 + e (e=0..7).
// Element index: b*4096 + kk*128 + nt*64 + lane. n==21 -> 1.0 (row-sum), >21 -> 0.
__global__ __launch_bounds__(256) void bpack2_kernel(const float* __restrict__ prob,
                                                     uint4* __restrict__ bp) {
    int idx = blockIdx.x * 256 + threadIdx.x;        // 0 .. 16383
    if (idx >= BZ * 32 * 2 * 64) return;
    int lane = idx & 63;
    int nt   = (idx >> 6) & 1;
    int kk   = (idx >> 7) & 31;
    int b    = idx >> 12;
    int n    = (lane & 15) + nt * 16;
    int k0   = kk * 32 + ((lane >> 4) << 3);
    unsigned int h[8];
#pragma unroll
    for (int e = 0; e < 8; ++e) {
        float v;
        if (n < C_N)       v = prob[((size_t)b * TOKEN_N + (k0 + e)) * C_N + n];
        else if (n == C_N) v = 1.0f;
        else               v = 0.0f;
        h[e] = f2bf(v);
    }
    uint4 o;
    o.x = h[0] | (h[1] << 16);
    o.y = h[2] | (h[3] << 16);
    o.z = h[4] | (h[5] << 16);
    o.w = h[6] | (h[7] << 16);
    bp[idx] = o;
}

// ---------------- kernel 3: depth-D register-pipelined LDS-staged MFMA pass ----------------
// Each WAVE (independent, no barriers) owns 16 rows x K=1024. D chunks (4.25KB each)
// kept in flight in named register sets; LDS double-buffered at row stride 68 floats
// (banks 4r mod 32 -> 2-way = free for b128 fragment reads).
template<bool ENC>
__device__ __forceinline__ void rows_body(const float* __restrict__ base, int mm, int lane,
                                          int i0, const uint4* __restrict__ bp,
                                          float* __restrict__ acc, float* __restrict__ ldsw) {
    constexpr int NSLOT = ENC ? 5 : 4;     // staging float4-issues per chunk
    constexpr int D     = ENC ? 3 : 4;     // chunks in flight
    constexpr int RS    = 68;              // LDS row stride (floats)
    const int b = (mm >> 3) & 3;

    // ---- per-lane staging source pointers (chunk 0), 16B-aligned ----
    const float* gs[NSLOT];
    int lt[NSLOT];                          // LDS float offset per slot (x4 floats per lane)
#pragma unroll
    for (int s = 0; s < NSLOT; ++s) {
        if constexpr (ENC) {
            int t = (s == 4) ? (256 + (lane & 15)) : (s * 64 + lane);
            int row = t / 17, u = t - row * 17;
            size_t start = (size_t)mm * 1050625u + (size_t)(1 + i0 + row) * 1025u + 1u;
            int delta = (int)(start & 3);
            size_t gidx = start - delta + (size_t)u * 4;
            if (s == 4 && gidx > (size_t)(ENC_TOT - 964)) gidx = ENC_TOT - 964; // tail clamp; clamped bytes unused (delta=0 row)
            gs[s] = base + gidx;
            lt[s] = t * 4;                  // linear: row*68 + u*4
        } else {
            int t = s * 64 + lane;
            int row = t >> 4, u = t & 15;
            gs[s] = base + (size_t)mm * 1048576u + (size_t)(i0 + row) * 1024u + (size_t)u * 4;
            lt[s] = row * RS + u * 4;       // padded stride 68
        }
    }

    float4 G[D][NSLOT];                     // fully-static indices only (full unroll)
    uint4  Bb[2][4];
    const uint4* bpp = bp + (size_t)b * 4096 + lane;

    // ---- fragment read base in LDS window ----
    const int r = lane & 15, kg = lane >> 4;
    int fragbase;
    if constexpr (ENC) fragbase = r * RS + ((mm + i0 + r + 2) & 3) + kg * 8;
    else               fragbase = r * RS + kg * 8;

    f32x4 c0 = {0.f, 0.f, 0.f, 0.f};
    f32x4 c1 = {0.f, 0.f, 0.f, 0.f};

    auto KSTEP = [&](const float* lf, int j0, uint4 bb0, uint4 bb1) {
        float a0, a1, a2, a3, a4, a5, a6, a7;
        if constexpr (ENC) {
            const float* p = lf + fragbase + j0;
            a0 = p[0]; a1 = p[1]; a2 = p[2]; a3 = p[3];
            a4 = p[4]; a5 = p[5]; a6 = p[6]; a7 = p[7];
        } else {
            float4 lo = *reinterpret_cast<const float4*>(lf + fragbase + j0);
            float4 hi = *reinterpret_cast<const float4*>(lf + fragbase + j0 + 4);
            a0 = lo.x; a1 = lo.y; a2 = lo.z; a3 = lo.w;
            a4 = hi.x; a5 = hi.y; a6 = hi.z; a7 = hi.w;
        }
        uint4 aw;
        aw.x = f2bf(a0) | (f2bf(a1) << 16);
        aw.y = f2bf(a2) | (f2bf(a3) << 16);
        aw.z = f2bf(a4) | (f2bf(a5) << 16);
        aw.w = f2bf(a6) | (f2bf(a7) << 16);
        short8 af = __builtin_bit_cast(short8, aw);
        c0 = __builtin_amdgcn_mfma_f32_16x16x32_bf16(af, __builtin_bit_cast(short8, bb0), c0, 0, 0, 0);
        c1 = __builtin_amdgcn_mfma_f32_16x16x32_bf16(af, __builtin_bit_cast(short8, bb1), c1, 0, 0, 0);
    };

    // ---- prologue: fill the register pipeline ----
#pragma unroll
    for (int s = 0; s < D; ++s)
#pragma unroll
        for (int q = 0; q < NSLOT; ++q)
            G[s][q] = *reinterpret_cast<const float4*>(gs[q] + s * 64);
#pragma unroll
    for (int q = 0; q < 4; ++q) Bb[0][q] = bpp[q * 64];
    {   // write chunk 0 (waits only its own loads; counted vmcnt)
        float* d0 = ldsw;
#pragma unroll
        for (int q = 0; q < NSLOT; ++q)
            *reinterpret_cast<float4*>(d0 + lt[q]) = G[0][q];
    }
#pragma unroll
    for (int q = 0; q < 4; ++q) Bb[1][q] = bpp[256 + q * 64];

    // ---- main loop, FULLY unrolled: all G/Bb indices compile-time ----
#pragma unroll
    for (int k = 0; k < 16; ++k) {
        const float* lf = ldsw + (k & 1) * 1088;
        KSTEP(lf, 0,  Bb[k & 1][0], Bb[k & 1][1]);
        KSTEP(lf, 32, Bb[k & 1][2], Bb[k & 1][3]);
        if (k < 15) {                       // stage chunk k+1 (arrived D-1 iters ago)
            float* d = ldsw + ((k + 1) & 1) * 1088;
#pragma unroll
            for (int q = 0; q < NSLOT; ++q)
                *reinterpret_cast<float4*>(d + lt[q]) = G[(k + 1) % D][q];
        }
        if (k + D < 16) {                   // refill freed register set with chunk k+D
#pragma unroll
            for (int q = 0; q < NSLOT; ++q)
                G[k % D][q] = *reinterpret_cast<const float4*>(gs[q] + (k + D) * 64);
        }
        if (k + 2 < 16) {                   // B double-buffer refill
#pragma unroll
            for (int q = 0; q < 4; ++q) Bb[k & 1][q] = bpp[(k + 2) * 256 + q * 64];
        }
    }

    // ---- epilogue: D layout (m89): col = lane&15, row = (lane>>4)*4 + reg ----
#pragma unroll
    for (int rr = 0; rr < 4; ++rr) {
        float sv  = __shfl(c1[rr], (lane & 48) + 5);   // n==21 lane of this row group
        float inv = 1.0f / sv;
        int i = i0 + kg * 4 + rr;
        float* ao = acc + ((size_t)b * TOKEN_N + i) * C_N;
        unsafeAtomicAdd(&ao[r], c0[rr] * inv);
        if (r < C_N - 16) unsafeAtomicAdd(&ao[16 + r], c1[rr] * inv);
    }
}

__global__ __launch_bounds__(256) void rows6_kernel(const float* __restrict__ attns,
                                                    const float* __restrict__ dattns,
                                                    const uint4* __restrict__ bp,
                                                    float* __restrict__ acc) {
    __shared__ __align__(16) float lds[8704];          // 4 waves x 2 bufs x 1088 floats
    const int lane = threadIdx.x & 63;
    const int wv   = threadIdx.x >> 6;
    float* ldsw = lds + wv * 2176;
    const int wid  = blockIdx.x * 4 + wv;              // 0..8191
    const int m    = wid >> 6;                          // 0..127 (block-uniform)
    const int i0   = (wid & 63) << 4;                   // row base (16 rows/wave)
    if (m < 64) rows_body<true >(attns,  m,      lane, i0, bp, acc, ldsw);
    else        rows_body<false>(dattns, m - 64, lane, i0, bp, acc, ldsw);
}

// ---------------- kernel 4: masked L1 loss + ROI count, block-reduced ----------------
__global__ __launch_bounds__(256) void loss_kernel(const float* __restrict__ prob,
                                                   const float* __restrict__ acc,
                                                   const int* __restrict__ roi,
                                                   float* __restrict__ scal) {
    int t = blockIdx.x * 256 + threadIdx.x;          // 0 .. BZ*TOKEN_N-1
    float lossp = 0.f, np = 0.f;
    if (t < BZ * TOKEN_N) {
        int rv = roi[t];
        np = (float)rv;
        const float* a = acc + (size_t)t * C_N;
        const float* p = prob + (size_t)t * C_N;
        float S = 0.f;
#pragma unroll
        for (int c = 0; c < C_N; ++c) S += a[c];
        float invS = 1.f / S;
        float l = 0.f;
#pragma unroll
        for (int c = 0; c < C_N; ++c) l += fabsf(p[c] - a[c] * invS);
        lossp = rv ? l : 0.f;
    }
#pragma unroll
    for (int off = 32; off > 0; off >>= 1) {
        lossp += __shfl_down(lossp, off);
        np    += __shfl_down(np, off);
    }
    __shared__ float redL[4], redN[4];
    int lane = threadIdx.x & 63, wv = threadIdx.x >> 6;
    if (lane == 0) { redL[wv] = lossp; redN[wv] = np; }
    __syncthreads();
    if (threadIdx.x == 0) {
        float L  = redL[0] + redL[1] + redL[2] + redL[3];
        float NN = redN[0] + redN[1] + redN[2] + redN[3];
        unsafeAtomicAdd(&scal[0], L);
        unsafeAtomicAdd(&scal[1], NN);
    }
}

// ---------------- kernel 5: finalize scalar ----------------
__global__ void finalize_kernel(const float* __restrict__ scal, float* __restrict__ out) {
    float loss = scal[0], N = scal[1];
    out[0] = (N > 0.f) ? (loss / N) : loss;   // WEIGHT = 1.0
}

extern "C" void kernel_launch(void* const* d_in, const int* in_sizes, int n_in,
                              void* d_out, int out_size, void* d_ws, size_t ws_size,
                              hipStream_t stream) {
    const float* preds  = (const float*)d_in[0];
    const int*   roi    = (const int*)d_in[3];
    const float* attns  = (const float*)d_in[5];
    const float* dattns = (const float*)d_in[6];

    float* prob = (float*)d_ws;               // 86016 floats
    float* acc  = prob + PROB_ELEMS;          // 86016 floats
    float* scal = acc + PROB_ELEMS;           // 2 floats (loss, N)
    // B-pack buffer, 16B-aligned: 4 b * 32 kk * 2 nt * 64 lanes * 16 B = 256 KB
    uint4* bpack = (uint4*)((char*)d_ws + ((PROB_ELEMS * 2 + 2) * sizeof(float) + 15 & ~(size_t)15));

    hipMemsetAsync(acc, 0, (PROB_ELEMS + 2) * sizeof(float), stream);

    hipLaunchKernelGGL(softmax_kernel, dim3((BZ * TOKEN_N + 255) / 256), dim3(256), 0, stream,
                       preds, prob);
    hipLaunchKernelGGL(bpack2_kernel, dim3(64), dim3(256), 0, stream,
                       prob, bpack);
    hipLaunchKernelGGL(rows6_kernel, dim3(2048), dim3(256), 0, stream,
                       attns, dattns, bpack, acc);
    hipLaunchKernelGGL(loss_kernel, dim3((BZ * TOKEN_N + 255) / 256), dim3(256), 0, stream,
                       prob, acc, roi, scal);
    hipLaunchKernelGGL(finalize_kernel, dim3(1), dim3(1), 0, stream,
                       scal, (float*)d_out);
}

// Round 7
// 127.375 us; speedup vs baseline: 4.5680x; 1.0181x over previous
//
#include <hip/hip_runtime.h>
#include <cstdint>
#include <cstddef>

#define C_N     21
#define BZ      4
#define TOKEN_N 1024
#define TOTAL_N 1025
#define PROB_ELEMS (BZ * TOKEN_N * C_N)   // 86016
#define ENC_TOT  67240000ull              // floats in attns (2*4*8*1025*1025)

typedef short  short8 __attribute__((ext_vector_type(8)));
typedef float  f32x4  __attribute__((ext_vector_type(4)));

typedef __attribute__((address_space(1))) const unsigned int* gld_gp;
typedef __attribute__((address_space(3))) unsigned int*       gld_lp;

// fp32 -> bf16 round-to-nearest-even (non-negative normals only here)
static __device__ __forceinline__ unsigned int f2bf(float x) {
    unsigned int u = __float_as_uint(x);
    return (u + 0x7FFFu + ((u >> 16) & 1u)) >> 16;
}

// ---------------- kernel 1: softmax over C for each (b, token) ----------------
__global__ __launch_bounds__(256) void softmax_kernel(const float* __restrict__ preds,
                                                      float* __restrict__ prob) {
    int t = blockIdx.x * blockDim.x + threadIdx.x;   // 0 .. BZ*TOKEN_N-1
    if (t >= BZ * TOKEN_N) return;
    int b = t >> 10, j = t & 1023;
    const float* p = preds + (size_t)b * C_N * TOKEN_N + j;
    float v[C_N];
    float mx = -3.4e38f;
#pragma unroll
    for (int c = 0; c < C_N; ++c) { v[c] = p[(size_t)c * TOKEN_N]; mx = fmaxf(mx, v[c]); }
    float ss = 0.f;
#pragma unroll
    for (int c = 0; c < C_N; ++c) { v[c] = __expf(v[c] - mx); ss += v[c]; }
    float inv = 1.f / ss;
    float* o = prob + (size_t)t * C_N;
#pragma unroll
    for (int c = 0; c < C_N; ++c) o[c] = v[c] * inv;
}

// ---------------- kernel 2: pack prob (+ones col) into 16x16x32 B-fragments ----------------
// B[k][n]: lane l holds n = (l&15) + nt*16, k = kk*32 + (l>>4)*8 + e (e=0..7).
// Element index: b*4096 + kk*128 + nt*64 + lane. n==21 -> 1.0 (row-sum), >21 -> 0.
__global__ __launch_bounds__(256) void bpack2_kernel(const float* __restrict__ prob,
                                                     uint4* __restrict__ bp) {
    int idx = blockIdx.x * 256 + threadIdx.x;        // 0 .. 16383
    if (idx >= BZ * 32 * 2 * 64) return;
    int lane = idx & 63;
    int nt   = (idx >> 6) & 1;
    int kk   = (idx >> 7) & 31;
    int b    = idx >> 12;
    int n    = (lane & 15) + nt * 16;
    int k0   = kk * 32 + ((lane >> 4) << 3);
    unsigned int h[8];
#pragma unroll
    for (int e = 0; e < 8; ++e) {
        float v;
        if (n < C_N)       v = prob[((size_t)b * TOKEN_N + (k0 + e)) * C_N + n];
        else if (n == C_N) v = 1.0f;
        else               v = 0.0f;
        h[e] = f2bf(v);
    }
    uint4 o;
    o.x = h[0] | (h[1] << 16);
    o.y = h[2] | (h[3] << 16);
    o.z = h[4] | (h[5] << 16);
    o.w = h[6] | (h[7] << 16);
    bp[idx] = o;
}

// ---------------- kernel 3: WG-per-stripe, linear global_load_lds bulk staging ----------------
// WG (4 waves) owns one CONTIGUOUS 16-row stripe (~65KB). Stage whole stripe to LDS
// via global_load_lds width-16 (sequential 1KB runs -> DRAM-friendly), one barrier,
// K split across waves (8 K-steps each, B preloaded to regs), LDS partial-D reduce,
// wave 0 normalizes + atomics.
template<bool ENC>
__device__ __forceinline__ void rows_body(const float* __restrict__ base, int mm, int i0,
                                          const uint4* __restrict__ bp,
                                          float* __restrict__ acc, float* __restrict__ lds) {
    const int tid  = threadIdx.x;
    const int lane = tid & 63;
    const int w    = tid >> 6;               // wave 0..3
    const int b    = (mm >> 3) & 3;

    // ---- stage stripe into LDS (linear image) ----
    int delta = 0;
    if constexpr (ENC) {
        // needed floats: g[S0 + r*1025 + k], r=0..15, k=0..1023 (A[i0+r][1+k])
        const size_t S0 = (size_t)mm * 1050625ull + (size_t)(1 + i0) * 1025ull + 1ull;
        const size_t aligned = S0 & ~(size_t)3;
        delta = (int)(S0 - aligned);
        const int nInstr = (w < 3) ? 17 : 14;        // 65 instrs total, 256 floats each
        const int e0 = w * 17;
        for (int q = 0; q < nInstr; ++q) {           // wave-uniform trip count
            const int e = e0 + q;
            size_t gb  = aligned + (size_t)e * 256;
            int   ldso = e * 256;
            if (gb + 256 > ENC_TOT) {                // tail clamp: shift BOTH bases equally
                size_t d = gb + 256 - ENC_TOT;
                gb -= d; ldso -= (int)d;
            }
            __builtin_amdgcn_global_load_lds((gld_gp)(base + gb + (size_t)lane * 4),
                                             (gld_lp)&lds[ldso], 16, 0, 0);
        }
    } else {
        // 16 rows x 4KB, LDS row stride 1028 floats (pad between rows; 2-way-free b128)
        const size_t sb = (size_t)mm * 1048576ull + (size_t)i0 * 1024ull;
#pragma unroll
        for (int q = 0; q < 16; ++q) {
            const int e = w * 16 + q;                // 0..63
            const int row = e >> 2, sub = e & 3;
            const size_t gb = sb + (size_t)row * 1024 + (size_t)sub * 256;
            const int ldso  = row * 1028 + sub * 256;
            __builtin_amdgcn_global_load_lds((gld_gp)(base + gb + (size_t)lane * 4),
                                             (gld_lp)&lds[ldso], 16, 0, 0);
        }
    }

    // ---- preload this wave's B-fragments (K-steps w*8 .. w*8+7), L2-hot ----
    const uint4* bpp = bp + (size_t)b * 4096 + lane;
    uint4 Bq[8][2];
#pragma unroll
    for (int s = 0; s < 8; ++s) {
        Bq[s][0] = bpp[(w * 8 + s) * 128];
        Bq[s][1] = bpp[(w * 8 + s) * 128 + 64];
    }

    __syncthreads();                                  // drains vmcnt (global_load_lds + Bq)

    // ---- compute: wave w handles K in [w*256, w*256+256) ----
    const int r = lane & 15, kg = lane >> 4;
    f32x4 c0 = {0.f, 0.f, 0.f, 0.f};
    f32x4 c1 = {0.f, 0.f, 0.f, 0.f};
#pragma unroll
    for (int s = 0; s < 8; ++s) {
        const int k0 = w * 256 + s * 32 + kg * 8;
        float a0, a1, a2, a3, a4, a5, a6, a7;
        if constexpr (ENC) {
            const float* p = lds + delta + r * 1025 + k0;   // odd stride: bank-staggered
            a0 = p[0]; a1 = p[1]; a2 = p[2]; a3 = p[3];
            a4 = p[4]; a5 = p[5]; a6 = p[6]; a7 = p[7];
        } else {
            const float* p = lds + r * 1028 + k0;           // 16B-aligned
            float4 lo = *reinterpret_cast<const float4*>(p);
            float4 hi = *reinterpret_cast<const float4*>(p + 4);
            a0 = lo.x; a1 = lo.y; a2 = lo.z; a3 = lo.w;
            a4 = hi.x; a5 = hi.y; a6 = hi.z; a7 = hi.w;
        }
        uint4 aw;
        aw.x = f2bf(a0) | (f2bf(a1) << 16);
        aw.y = f2bf(a2) | (f2bf(a3) << 16);
        aw.z = f2bf(a4) | (f2bf(a5) << 16);
        aw.w = f2bf(a6) | (f2bf(a7) << 16);
        short8 af = __builtin_bit_cast(short8, aw);
        c0 = __builtin_amdgcn_mfma_f32_16x16x32_bf16(af, __builtin_bit_cast(short8, Bq[s][0]), c0, 0, 0, 0);
        c1 = __builtin_amdgcn_mfma_f32_16x16x32_bf16(af, __builtin_bit_cast(short8, Bq[s][1]), c1, 0, 0, 0);
    }

    // ---- cross-wave partial-D reduce (stripe LDS is dead; alias it) ----
    __syncthreads();
    if (w != 0) {
        float* red = lds + w * 512 + lane * 8;
#pragma unroll
        for (int j = 0; j < 4; ++j) { red[j] = c0[j]; red[4 + j] = c1[j]; }
    }
    __syncthreads();
    if (w == 0) {
#pragma unroll
        for (int ww = 1; ww < 4; ++ww) {
            const float* red = lds + ww * 512 + lane * 8;
#pragma unroll
            for (int j = 0; j < 4; ++j) { c0[j] += red[j]; c1[j] += red[4 + j]; }
        }
        // D layout (m89): col = lane&15, row = (lane>>4)*4 + reg
#pragma unroll
        for (int rr = 0; rr < 4; ++rr) {
            float sv  = __shfl(c1[rr], (lane & 48) + 5);   // n==21 lane of this row group
            float inv = 1.0f / sv;
            int i = i0 + kg * 4 + rr;
            float* ao = acc + ((size_t)b * TOKEN_N + i) * C_N;
            unsafeAtomicAdd(&ao[r], c0[rr] * inv);
            if (r < C_N - 16) unsafeAtomicAdd(&ao[16 + r], c1[rr] * inv);
        }
    }
}

__global__ __launch_bounds__(256) void rows7_kernel(const float* __restrict__ attns,
                                                    const float* __restrict__ dattns,
                                                    const uint4* __restrict__ bp,
                                                    float* __restrict__ acc) {
    __shared__ __align__(16) float lds[16640];        // 66.6 KB -> 2 WGs/CU
    const int wid = blockIdx.x;                        // 0..8191
    const int m   = wid >> 6;                          // 0..127
    const int i0  = (wid & 63) << 4;                   // stripe base row
    if (m < 64) rows_body<true >(attns,  m,      i0, bp, acc, lds);
    else        rows_body<false>(dattns, m - 64, i0, bp, acc, lds);
}

// ---------------- kernel 4: masked L1 loss + ROI count, block-reduced ----------------
__global__ __launch_bounds__(256) void loss_kernel(const float* __restrict__ prob,
                                                   const float* __restrict__ acc,
                                                   const int* __restrict__ roi,
                                                   float* __restrict__ scal) {
    int t = blockIdx.x * 256 + threadIdx.x;          // 0 .. BZ*TOKEN_N-1
    float lossp = 0.f, np = 0.f;
    if (t < BZ * TOKEN_N) {
        int rv = roi[t];
        np = (float)rv;
        const float* a = acc + (size_t)t * C_N;
        const float* p = prob + (size_t)t * C_N;
        float S = 0.f;
#pragma unroll
        for (int c = 0; c < C_N; ++c) S += a[c];
        float invS = 1.f / S;
        float l = 0.f;
#pragma unroll
        for (int c = 0; c < C_N; ++c) l += fabsf(p[c] - a[c] * invS);
        lossp = rv ? l : 0.f;
    }
#pragma unroll
    for (int off = 32; off > 0; off >>= 1) {
        lossp += __shfl_down(lossp, off);
        np    += __shfl_down(np, off);
    }
    __shared__ float redL[4], redN[4];
    int lane = threadIdx.x & 63, wv = threadIdx.x >> 6;
    if (lane == 0) { redL[wv] = lossp; redN[wv] = np; }
    __syncthreads();
    if (threadIdx.x == 0) {
        float L  = redL[0] + redL[1] + redL[2] + redL[3];
        float NN = redN[0] + redN[1] + redN[2] + redN[3];
        unsafeAtomicAdd(&scal[0], L);
        unsafeAtomicAdd(&scal[1], NN);
    }
}

// ---------------- kernel 5: finalize scalar ----------------
__global__ void finalize_kernel(const float* __restrict__ scal, float* __restrict__ out) {
    float loss = scal[0], N = scal[1];
    out[0] = (N > 0.f) ? (loss / N) : loss;   // WEIGHT = 1.0
}

extern "C" void kernel_launch(void* const* d_in, const int* in_sizes, int n_in,
                              void* d_out, int out_size, void* d_ws, size_t ws_size,
                              hipStream_t stream) {
    const float* preds  = (const float*)d_in[0];
    const int*   roi    = (const int*)d_in[3];
    const float* attns  = (const float*)d_in[5];
    const float* dattns = (const float*)d_in[6];

    float* prob = (float*)d_ws;               // 86016 floats
    float* acc  = prob + PROB_ELEMS;          // 86016 floats
    float* scal = acc + PROB_ELEMS;           // 2 floats (loss, N)
    // B-pack buffer, 16B-aligned: 4 b * 32 kk * 2 nt * 64 lanes * 16 B = 256 KB
    uint4* bpack = (uint4*)((char*)d_ws + ((PROB_ELEMS * 2 + 2) * sizeof(float) + 15 & ~(size_t)15));

    hipMemsetAsync(acc, 0, (PROB_ELEMS + 2) * sizeof(float), stream);

    hipLaunchKernelGGL(softmax_kernel, dim3((BZ * TOKEN_N + 255) / 256), dim3(256), 0, stream,
                       preds, prob);
    hipLaunchKernelGGL(bpack2_kernel, dim3(64), dim3(256), 0, stream,
                       prob, bpack);
    hipLaunchKernelGGL(rows7_kernel, dim3(8192), dim3(256), 0, stream,
                       attns, dattns, bpack, acc);
    hipLaunchKernelGGL(loss_kernel, dim3((BZ * TOKEN_N + 255) / 256), dim3(256), 0, stream,
                       prob, acc, roi, scal);
    hipLaunchKernelGGL(finalize_kernel, dim3(1), dim3(1), 0, stream,
                       scal, (float*)d_out);
}

// Round 8
// 120.127 us; speedup vs baseline: 4.8436x; 1.0603x over previous
//
#include <hip/hip_runtime.h>
#include <cstdint>
#include <cstddef>

#define C_N     21
#define BZ      4
#define TOKEN_N 1024
#define TOTAL_N 1025
#define PROB_ELEMS (BZ * TOKEN_N * C_N)   // 86016
#define ENC_TOT  67240000ull              // floats in attns (2*4*8*1025*1025)

typedef short  short8 __attribute__((ext_vector_type(8)));
typedef float  f32x4  __attribute__((ext_vector_type(4)));

typedef __attribute__((address_space(1))) const unsigned int* gld_gp;
typedef __attribute__((address_space(3))) unsigned int*       gld_lp;

// fp32 -> bf16 round-to-nearest-even (non-negative normals only here)
static __device__ __forceinline__ unsigned int f2bf(float x) {
    unsigned int u = __float_as_uint(x);
    return (u + 0x7FFFu + ((u >> 16) & 1u)) >> 16;
}

// ---------------- kernel 1: fused softmax + B-fragment pack ----------------
// 128 blocks (4 b x 32 kk) x 128 threads. Threads 0..31: softmax for one token each
// (token j = kk*32+tid) -> global prob + LDS sm[32][33] (col 21 = 1.0, cols 22.. = 0).
// Then 2 nt-sets x 64 lanes pack B[k][n] fragments for 16x16x32 MFMA:
// lane l holds n=(l&15)+nt*16, k = kk*32 + (l>>4)*8 + e.
__global__ __launch_bounds__(128) void sb_kernel(const float* __restrict__ preds,
                                                 float* __restrict__ prob,
                                                 uint4* __restrict__ bp) {
    const int b  = blockIdx.x >> 5;
    const int kk = blockIdx.x & 31;
    const int tid = threadIdx.x;
    __shared__ float sm[32][33];

    if (tid < 32) {
        const int j = kk * 32 + tid;
        const float* p = preds + (size_t)b * C_N * TOKEN_N + j;
        float v[C_N];
        float mx = -3.4e38f;
#pragma unroll
        for (int c = 0; c < C_N; ++c) { v[c] = p[(size_t)c * TOKEN_N]; mx = fmaxf(mx, v[c]); }
        float ss = 0.f;
#pragma unroll
        for (int c = 0; c < C_N; ++c) { v[c] = __expf(v[c] - mx); ss += v[c]; }
        float inv = 1.f / ss;
        float* o = prob + ((size_t)b * TOKEN_N + j) * C_N;
#pragma unroll
        for (int c = 0; c < C_N; ++c) { float pv = v[c] * inv; o[c] = pv; sm[tid][c] = pv; }
        sm[tid][C_N] = 1.0f;
#pragma unroll
        for (int c = C_N + 1; c < 32; ++c) sm[tid][c] = 0.f;
    }
    __syncthreads();

    const int lane = tid & 63;
    const int nt   = tid >> 6;
    const int n    = (lane & 15) + nt * 16;
    const int kl   = (lane >> 4) << 3;     // local k base 0..24
    unsigned int h[8];
#pragma unroll
    for (int e = 0; e < 8; ++e) h[e] = f2bf(sm[kl + e][n]);
    uint4 o;
    o.x = h[0] | (h[1] << 16);
    o.y = h[2] | (h[3] << 16);
    o.z = h[4] | (h[5] << 16);
    o.w = h[6] | (h[7] << 16);
    bp[(size_t)b * 4096 + kk * 128 + nt * 64 + lane] = o;
}

// ---------------- kernel 2: WG-per-stripe, linear global_load_lds staging (NT) ----------------
// Identical structure to round 7, but staging carries CPol NT (aux=2): stream the
// 537MB attention data without L3 retention -> every replay reads HBM at the
// (hypothesized higher) pure-read rate. B-fragments stay cached (heavy reuse).
template<bool ENC>
__device__ __forceinline__ void rows_body(const float* __restrict__ base, int mm, int i0,
                                          const uint4* __restrict__ bp,
                                          float* __restrict__ acc, float* __restrict__ lds) {
    const int tid  = threadIdx.x;
    const int lane = tid & 63;
    const int w    = tid >> 6;               // wave 0..3
    const int b    = (mm >> 3) & 3;

    // ---- stage stripe into LDS (linear image), NT policy ----
    int delta = 0;
    if constexpr (ENC) {
        const size_t S0 = (size_t)mm * 1050625ull + (size_t)(1 + i0) * 1025ull + 1ull;
        const size_t aligned = S0 & ~(size_t)3;
        delta = (int)(S0 - aligned);
        const int nInstr = (w < 3) ? 17 : 14;        // 65 instrs total, 256 floats each
        const int e0 = w * 17;
        for (int q = 0; q < nInstr; ++q) {           // wave-uniform trip count
            const int e = e0 + q;
            size_t gb  = aligned + (size_t)e * 256;
            int   ldso = e * 256;
            if (gb + 256 > ENC_TOT) {                // tail clamp: shift BOTH bases equally
                size_t d = gb + 256 - ENC_TOT;
                gb -= d; ldso -= (int)d;
            }
            __builtin_amdgcn_global_load_lds((gld_gp)(base + gb + (size_t)lane * 4),
                                             (gld_lp)&lds[ldso], 16, 0, 2 /*NT*/);
        }
    } else {
        const size_t sb = (size_t)mm * 1048576ull + (size_t)i0 * 1024ull;
#pragma unroll
        for (int q = 0; q < 16; ++q) {
            const int e = w * 16 + q;                // 0..63
            const int row = e >> 2, sub = e & 3;
            const size_t gb = sb + (size_t)row * 1024 + (size_t)sub * 256;
            const int ldso  = row * 1028 + sub * 256;
            __builtin_amdgcn_global_load_lds((gld_gp)(base + gb + (size_t)lane * 4),
                                             (gld_lp)&lds[ldso], 16, 0, 2 /*NT*/);
        }
    }

    // ---- preload this wave's B-fragments (K-steps w*8 .. w*8+7), L2-hot ----
    const uint4* bpp = bp + (size_t)b * 4096 + lane;
    uint4 Bq[8][2];
#pragma unroll
    for (int s = 0; s < 8; ++s) {
        Bq[s][0] = bpp[(w * 8 + s) * 128];
        Bq[s][1] = bpp[(w * 8 + s) * 128 + 64];
    }

    __syncthreads();                                  // drains vmcnt (global_load_lds + Bq)

    // ---- compute: wave w handles K in [w*256, w*256+256) ----
    const int r = lane & 15, kg = lane >> 4;
    f32x4 c0 = {0.f, 0.f, 0.f, 0.f};
    f32x4 c1 = {0.f, 0.f, 0.f, 0.f};
#pragma unroll
    for (int s = 0; s < 8; ++s) {
        const int k0 = w * 256 + s * 32 + kg * 8;
        float a0, a1, a2, a3, a4, a5, a6, a7;
        if constexpr (ENC) {
            const float* p = lds + delta + r * 1025 + k0;   // odd stride: bank-staggered
            a0 = p[0]; a1 = p[1]; a2 = p[2]; a3 = p[3];
            a4 = p[4]; a5 = p[5]; a6 = p[6]; a7 = p[7];
        } else {
            const float* p = lds + r * 1028 + k0;           // 16B-aligned
            float4 lo = *reinterpret_cast<const float4*>(p);
            float4 hi = *reinterpret_cast<const float4*>(p + 4);
            a0 = lo.x; a1 = lo.y; a2 = lo.z; a3 = lo.w;
            a4 = hi.x; a5 = hi.y; a6 = hi.z; a7 = hi.w;
        }
        uint4 aw;
        aw.x = f2bf(a0) | (f2bf(a1) << 16);
        aw.y = f2bf(a2) | (f2bf(a3) << 16);
        aw.z = f2bf(a4) | (f2bf(a5) << 16);
        aw.w = f2bf(a6) | (f2bf(a7) << 16);
        short8 af = __builtin_bit_cast(short8, aw);
        c0 = __builtin_amdgcn_mfma_f32_16x16x32_bf16(af, __builtin_bit_cast(short8, Bq[s][0]), c0, 0, 0, 0);
        c1 = __builtin_amdgcn_mfma_f32_16x16x32_bf16(af, __builtin_bit_cast(short8, Bq[s][1]), c1, 0, 0, 0);
    }

    // ---- cross-wave partial-D reduce (stripe LDS is dead; alias it) ----
    __syncthreads();
    if (w != 0) {
        float* red = lds + w * 512 + lane * 8;
#pragma unroll
        for (int j = 0; j < 4; ++j) { red[j] = c0[j]; red[4 + j] = c1[j]; }
    }
    __syncthreads();
    if (w == 0) {
#pragma unroll
        for (int ww = 1; ww < 4; ++ww) {
            const float* red = lds + ww * 512 + lane * 8;
#pragma unroll
            for (int j = 0; j < 4; ++j) { c0[j] += red[j]; c1[j] += red[4 + j]; }
        }
        // D layout (m89): col = lane&15, row = (lane>>4)*4 + reg
#pragma unroll
        for (int rr = 0; rr < 4; ++rr) {
            float sv  = __shfl(c1[rr], (lane & 48) + 5);   // n==21 lane of this row group
            float inv = 1.0f / sv;
            int i = i0 + kg * 4 + rr;
            float* ao = acc + ((size_t)b * TOKEN_N + i) * C_N;
            unsafeAtomicAdd(&ao[r], c0[rr] * inv);
            if (r < C_N - 16) unsafeAtomicAdd(&ao[16 + r], c1[rr] * inv);
        }
    }
}

__global__ __launch_bounds__(256) void rows8_kernel(const float* __restrict__ attns,
                                                    const float* __restrict__ dattns,
                                                    const uint4* __restrict__ bp,
                                                    float* __restrict__ acc) {
    __shared__ __align__(16) float lds[16640];        // 66.6 KB -> 2 WGs/CU
    const int wid = blockIdx.x;                        // 0..8191
    const int m   = wid >> 6;                          // 0..127
    const int i0  = (wid & 63) << 4;                   // stripe base row
    if (m < 64) rows_body<true >(attns,  m,      i0, bp, acc, lds);
    else        rows_body<false>(dattns, m - 64, i0, bp, acc, lds);
}

// ---------------- kernel 3: masked L1 loss + ROI count + last-block finalize ----------------
__global__ __launch_bounds__(256) void loss2_kernel(const float* __restrict__ prob,
                                                    const float* __restrict__ acc,
                                                    const int* __restrict__ roi,
                                                    float* __restrict__ scal,
                                                    int* __restrict__ cnt,
                                                    float* __restrict__ out,
                                                    int nblocks) {
    int t = blockIdx.x * 256 + threadIdx.x;          // 0 .. BZ*TOKEN_N-1
    float lossp = 0.f, np = 0.f;
    if (t < BZ * TOKEN_N) {
        int rv = roi[t];
        np = (float)rv;
        const float* a = acc + (size_t)t * C_N;
        const float* p = prob + (size_t)t * C_N;
        float S = 0.f;
#pragma unroll
        for (int c = 0; c < C_N; ++c) S += a[c];
        float invS = 1.f / S;
        float l = 0.f;
#pragma unroll
        for (int c = 0; c < C_N; ++c) l += fabsf(p[c] - a[c] * invS);
        lossp = rv ? l : 0.f;
    }
#pragma unroll
    for (int off = 32; off > 0; off >>= 1) {
        lossp += __shfl_down(lossp, off);
        np    += __shfl_down(np, off);
    }
    __shared__ float redL[4], redN[4];
    int lane = threadIdx.x & 63, wv = threadIdx.x >> 6;
    if (lane == 0) { redL[wv] = lossp; redN[wv] = np; }
    __syncthreads();
    if (threadIdx.x == 0) {
        float L  = redL[0] + redL[1] + redL[2] + redL[3];
        float NN = redN[0] + redN[1] + redN[2] + redN[3];
        unsafeAtomicAdd(&scal[0], L);
        unsafeAtomicAdd(&scal[1], NN);
        __threadfence();                               // make adds visible device-wide
        int prev = atomicAdd(cnt, 1);
        if (prev == nblocks - 1) {                     // last block: finalize
            float loss = atomicAdd(&scal[0], 0.0f);    // coherent device-scope read
            float N    = atomicAdd(&scal[1], 0.0f);
            out[0] = (N > 0.f) ? (loss / N) : loss;    // WEIGHT = 1.0
        }
    }
}

extern "C" void kernel_launch(void* const* d_in, const int* in_sizes, int n_in,
                              void* d_out, int out_size, void* d_ws, size_t ws_size,
                              hipStream_t stream) {
    const float* preds  = (const float*)d_in[0];
    const int*   roi    = (const int*)d_in[3];
    const float* attns  = (const float*)d_in[5];
    const float* dattns = (const float*)d_in[6];

    float* prob = (float*)d_ws;               // 86016 floats
    float* acc  = prob + PROB_ELEMS;          // 86016 floats
    float* scal = acc + PROB_ELEMS;           // 2 floats (loss, N)
    int*   cnt  = (int*)(scal + 2);           // completion counter
    // B-pack buffer, 16B-aligned: 4 b * 32 kk * 2 nt * 64 lanes * 16 B = 256 KB
    uint4* bpack = (uint4*)((char*)d_ws + ((PROB_ELEMS * 2 + 4) * sizeof(float) + 15 & ~(size_t)15));

    // zero acc + scal + cnt every launch (graph-replayed)
    hipMemsetAsync(acc, 0, (PROB_ELEMS + 3) * sizeof(float), stream);

    hipLaunchKernelGGL(sb_kernel, dim3(BZ * 32), dim3(128), 0, stream,
                       preds, prob, bpack);
    hipLaunchKernelGGL(rows8_kernel, dim3(8192), dim3(256), 0, stream,
                       attns, dattns, bpack, acc);
    const int LB = (BZ * TOKEN_N + 255) / 256;
    hipLaunchKernelGGL(loss2_kernel, dim3(LB), dim3(256), 0, stream,
                       prob, acc, roi, scal, cnt, (float*)d_out, LB);
}